// Round 1
// baseline (676.249 us; speedup 1.0000x reference)
//
#include <hip/hip_runtime.h>
#include <hip/hip_bf16.h>
#include <math.h>

typedef __bf16 bf16_t;
typedef bf16_t bf16x4 __attribute__((ext_vector_type(4)));
typedef bf16_t bf16x8 __attribute__((ext_vector_type(8)));
typedef float  f32x4  __attribute__((ext_vector_type(4)));

static constexpr int Bn = 16384;
static constexpr int Hn = 512;

__device__ __forceinline__ float sigm(float x) { return 1.0f / (1.0f + __expf(-x)); }

// C[M,N] = epilogue(A[M,K] @ Bm[K,N] + bias)
// A is fp32, split into A0 (k < kSplit) and A1 (k >= kSplit). Bm fp32 row-major KxN.
// Tile: 128x128, BK=32, 256 threads = 4 waves in 2x2, each wave 64x64 via 4x4 MFMA frags.
template<int EPI>
__global__ void gemm_mfma(const float* __restrict__ A0,
                          const float* __restrict__ A1,
                          int kSplit, int lda0, int lda1,
                          const float* __restrict__ Bm, int ldb,
                          const float* __restrict__ bias,
                          int K,
                          bf16_t* __restrict__ gates,
                          float* __restrict__ outp,
                          const float* __restrict__ cell)
{
    // row stride 40 bf16 (80B, 16B-aligned, breaks pow2 bank stride)
    __shared__ bf16_t sA[128 * 40];   // sA[m][k]
    __shared__ bf16_t sB[128 * 40];   // sB[n][k]  (B transposed)

    const int tid  = threadIdx.x;
    const int lane = tid & 63;
    const int wid  = tid >> 6;
    const int wr   = wid >> 1;        // wave row (0..1)
    const int wc   = wid & 1;         // wave col (0..1)
    const int row0 = blockIdx.y * 128;
    const int col0 = blockIdx.x * 128;

    f32x4 acc[4][4] = {};

    const int nk = K >> 5;
    for (int kt = 0; kt < nk; ++kt) {
        const int k0 = kt << 5;
        // ---- stage A tile: 128x32 fp32 -> bf16 LDS. 4 float4 per thread.
        {
            const int achunk = tid & 7;           // which group of 4 k's
            const int gk = k0 + achunk * 4;
            const float* abase;
            int kk, ldx;
            if (gk < kSplit) { abase = A0; kk = gk;          ldx = lda0; }
            else             { abase = A1; kk = gk - kSplit; ldx = lda1; }
#pragma unroll
            for (int r = 0; r < 4; ++r) {
                const int arow = (tid >> 3) + 32 * r;
                const float4 f = *(const float4*)(abase + (size_t)(row0 + arow) * ldx + kk);
                bf16x4 h;
                h[0] = (bf16_t)f.x; h[1] = (bf16_t)f.y; h[2] = (bf16_t)f.z; h[3] = (bf16_t)f.w;
                *(bf16x4*)&sA[arow * 40 + achunk * 4] = h;
            }
        }
        // ---- stage B tile transposed: 32x128 fp32 -> sB[n][k] bf16.
        {
            const int bn = tid & 127;
            const int kg = tid >> 7;              // 0,1 -> k halves of 16
            const float* bsrc = Bm + (size_t)(k0 + kg * 16) * ldb + col0 + bn;
            bf16x8 w0, w1;
#pragma unroll
            for (int j = 0; j < 8; ++j) {
                w0[j] = (bf16_t)bsrc[(size_t)j * ldb];
                w1[j] = (bf16_t)bsrc[(size_t)(j + 8) * ldb];
            }
            *(bf16x8*)&sB[bn * 40 + kg * 16]     = w0;
            *(bf16x8*)&sB[bn * 40 + kg * 16 + 8] = w1;
        }
        __syncthreads();

        // ---- fragments + MFMA (16x16x32: lane holds row/col = lane&15, k = 8*(lane>>4)+0..7)
        bf16x8 af[4], bfr[4];
#pragma unroll
        for (int i = 0; i < 4; ++i) {
            af[i]  = *(const bf16x8*)&sA[(wr * 64 + i * 16 + (lane & 15)) * 40 + (lane >> 4) * 8];
            bfr[i] = *(const bf16x8*)&sB[(wc * 64 + i * 16 + (lane & 15)) * 40 + (lane >> 4) * 8];
        }
#pragma unroll
        for (int i = 0; i < 4; ++i)
#pragma unroll
            for (int j = 0; j < 4; ++j)
                acc[i][j] = __builtin_amdgcn_mfma_f32_16x16x32_bf16(af[i], bfr[j], acc[i][j], 0, 0, 0);
        __syncthreads();
    }

    // ---- epilogue: C/D layout col = lane&15, row = 4*(lane>>4)+reg (m89-verified)
    const int lr = (lane >> 4) * 4;
    const int lc = lane & 15;
#pragma unroll
    for (int i = 0; i < 4; ++i) {
#pragma unroll
        for (int j = 0; j < 4; ++j) {
#pragma unroll
            for (int r = 0; r < 4; ++r) {
                const int grow = row0 + wr * 64 + i * 16 + lr + r;
                const int gcol = col0 + wc * 64 + j * 16 + lc;
                float v = acc[i][j][r];
                if constexpr (EPI == 0) {
                    // gates: i,f,o sigmoid; c (cols 1024..1535) tanh -> bf16
                    v += bias[gcol];
                    const float a = ((gcol >> 9) == 2) ? tanhf(v) : sigm(v);
                    gates[(size_t)grow * 2048 + gcol] = (bf16_t)a;
                } else if constexpr (EPI == 1) {
                    // attention logits (pre-softmax), fp32
                    outp[(size_t)grow * 4096 + gcol] = v + bias[gcol];
                } else {
                    // memory_read + fused LSTM cell update
                    const float ig = (float)gates[(size_t)grow * 2048 + gcol];
                    const float fg = (float)gates[(size_t)grow * 2048 + 512 + gcol];
                    const float cg = (float)gates[(size_t)grow * 2048 + 1024 + gcol];
                    const float og = (float)gates[(size_t)grow * 2048 + 1536 + gcol];
                    const float cv = cell[(size_t)grow * 512 + gcol];
                    const float ncv = fg * cv + ig * cg + 0.1f * v;
                    const float nhv = og * tanhf(ncv);
                    outp[(size_t)grow * 512 + gcol] = nhv;                       // new_hidden
                    outp[(size_t)Bn * Hn + (size_t)grow * 512 + gcol] = ncv;     // new_cell
                }
            }
        }
    }
}

// In-place row softmax over 4096 columns; one 256-thread block per row, all data in regs.
__global__ void softmax_rows(float* __restrict__ attn)
{
    const int row = blockIdx.x;
    float* p = attn + (size_t)row * 4096;
    const int tid = threadIdx.x;
    float4 v[4];
#pragma unroll
    for (int i = 0; i < 4; ++i) v[i] = ((const float4*)p)[tid + 256 * i];

    float mx = -INFINITY;
#pragma unroll
    for (int i = 0; i < 4; ++i)
        mx = fmaxf(mx, fmaxf(fmaxf(v[i].x, v[i].y), fmaxf(v[i].z, v[i].w)));
#pragma unroll
    for (int off = 32; off > 0; off >>= 1) mx = fmaxf(mx, __shfl_xor(mx, off));

    __shared__ float smx[4], ssm[4];
    if ((tid & 63) == 0) smx[tid >> 6] = mx;
    __syncthreads();
    mx = fmaxf(fmaxf(smx[0], smx[1]), fmaxf(smx[2], smx[3]));

    float sum = 0.0f;
#pragma unroll
    for (int i = 0; i < 4; ++i) {
        v[i].x = __expf(v[i].x - mx); v[i].y = __expf(v[i].y - mx);
        v[i].z = __expf(v[i].z - mx); v[i].w = __expf(v[i].w - mx);
        sum += v[i].x + v[i].y + v[i].z + v[i].w;
    }
#pragma unroll
    for (int off = 32; off > 0; off >>= 1) sum += __shfl_xor(sum, off);
    if ((tid & 63) == 0) ssm[tid >> 6] = sum;
    __syncthreads();
    sum = ssm[0] + ssm[1] + ssm[2] + ssm[3];

    const float inv = 1.0f / sum;
#pragma unroll
    for (int i = 0; i < 4; ++i) {
        v[i].x *= inv; v[i].y *= inv; v[i].z *= inv; v[i].w *= inv;
        ((float4*)p)[tid + 256 * i] = v[i];
    }
}

extern "C" void kernel_launch(void* const* d_in, const int* in_sizes, int n_in,
                              void* d_out, int out_size, void* d_ws, size_t ws_size,
                              hipStream_t stream)
{
    const float* input  = (const float*)d_in[0];   // (B, 512)
    const float* hidden = (const float*)d_in[1];   // (B, 512)
    const float* cell   = (const float*)d_in[2];   // (B, 512)
    const float* Wg     = (const float*)d_in[3];   // (1024, 2048)
    const float* bg     = (const float*)d_in[4];   // (2048,)
    const float* Wa     = (const float*)d_in[5];   // (512, 4096)
    const float* ba     = (const float*)d_in[6];   // (4096,)
    const float* Mem    = (const float*)d_in[7];   // (4096, 512)

    float* out   = (float*)d_out;
    float* attn  = out + 2ull * Bn * Hn;           // (B, 4096) output region, reused for logits
    bf16_t* gates = (bf16_t*)d_ws;                 // (B, 2048) bf16 activated gates = 67 MB

    dim3 blk(256, 1, 1);

    // gates = act([input|hidden] @ W_gates + bg) -> ws (bf16)
    gemm_mfma<0><<<dim3(2048 / 128, Bn / 128), blk, 0, stream>>>(
        input, hidden, 512, 512, 512, Wg, 2048, bg, 1024, gates, nullptr, nullptr);

    // logits = hidden @ W_attn + ba -> d_out attn region (fp32)
    gemm_mfma<1><<<dim3(4096 / 128, Bn / 128), blk, 0, stream>>>(
        hidden, hidden, 512, 512, 512, Wa, 4096, ba, 512, nullptr, attn, nullptr);

    // softmax in-place
    softmax_rows<<<Bn, 256, 0, stream>>>(attn);

    // mr = attn @ memory; fused: new_cell = f*cell + i*c + 0.1*mr; new_hidden = o*tanh(new_cell)
    gemm_mfma<2><<<dim3(512 / 128, Bn / 128), blk, 0, stream>>>(
        attn, attn, 1 << 30, 4096, 4096, Mem, 512, nullptr, 4096, gates, out, cell);
}

// Round 2
// 537.723 us; speedup vs baseline: 1.2576x; 1.2576x over previous
//
#include <hip/hip_runtime.h>
#include <hip/hip_bf16.h>
#include <math.h>

typedef __bf16 bf16_t;
typedef bf16_t bf16x8 __attribute__((ext_vector_type(8)));
typedef float  f32x4  __attribute__((ext_vector_type(4)));

static constexpr int Bn = 16384;
static constexpr int Hn = 512;

__device__ __forceinline__ float sigm(float x) { return 1.0f / (1.0f + __expf(-x)); }

typedef __attribute__((address_space(3))) void lds_void;
typedef const __attribute__((address_space(1))) void gl_void;

__device__ __forceinline__ void glds16(const void* g, void* l) {
    __builtin_amdgcn_global_load_lds((gl_void*)g, (lds_void*)l, 16, 0, 0);
}

// comb[B][1024] bf16 = [input | hidden] converted
__global__ void convert_comb(const float* __restrict__ inp, const float* __restrict__ hid,
                             bf16_t* __restrict__ comb)
{
    size_t t = (size_t)blockIdx.x * blockDim.x + threadIdx.x;  // B*1024/8 threads
    size_t r = t >> 7;
    int c8 = (int)(t & 127);
    const float* src = (c8 < 64) ? (inp + r * 512 + c8 * 8) : (hid + r * 512 + (c8 - 64) * 8);
    float4 a = ((const float4*)src)[0];
    float4 b = ((const float4*)src)[1];
    bf16x8 o;
    o[0] = (bf16_t)a.x; o[1] = (bf16_t)a.y; o[2] = (bf16_t)a.z; o[3] = (bf16_t)a.w;
    o[4] = (bf16_t)b.x; o[5] = (bf16_t)b.y; o[6] = (bf16_t)b.z; o[7] = (bf16_t)b.w;
    *(bf16x8*)(comb + t * 8) = o;
}

// dst[C][R] bf16 = transpose(src[R][C] fp32)
__global__ void transpose_bf16(const float* __restrict__ src, bf16_t* __restrict__ dst,
                               int R, int C)
{
    __shared__ float tile[32][33];
    const int x0 = blockIdx.x * 32, y0 = blockIdx.y * 32;
    const int tx = threadIdx.x & 31, ty = threadIdx.x >> 5;   // ty 0..7
#pragma unroll
    for (int i = 0; i < 32; i += 8)
        tile[ty + i][tx] = src[(size_t)(y0 + ty + i) * C + x0 + tx];
    __syncthreads();
#pragma unroll
    for (int i = 0; i < 32; i += 8)
        dst[(size_t)(x0 + ty + i) * R + y0 + tx] = (bf16_t)tile[tx][ty + i];
}

// C[M,N] = epi(A @ Bt^T + bias). A: bf16 [M][lda] (or fp32 if AF32). Bt: bf16 [N][ldb] (K-major).
// 128x128 tile, BK=32, 4 waves 2x2, global_load_lds staging, XOR-swizzled LDS.
// EPI 0: activated gates -> bout stride 2048. EPI 1: bf16 logits -> bout stride 8192.
// EPI 2: fused LSTM cell update -> fout.
template<int EPI, bool AF32>
__global__ __launch_bounds__(256)
void gemm_glds(const void* __restrict__ Aptr, int lda,
               const bf16_t* __restrict__ Bt, int ldb,
               const float* __restrict__ bias, int K, int N,
               bf16_t* __restrict__ bout, float* __restrict__ fout,
               const bf16_t* __restrict__ gates, const float* __restrict__ cell)
{
    constexpr int ABYTES = AF32 ? 16384 : 8192;
    __shared__ __align__(16) char smem[ABYTES + 8192];
    bf16_t* sB = (bf16_t*)(smem + ABYTES);

    const int tid = threadIdx.x, lane = tid & 63, wid = tid >> 6;
    const int wr = wid >> 1, wc = wid & 1;

    // bijective XCD swizzle (all grids are multiples of 8)
    const int nwg = gridDim.x;
    int bid = blockIdx.x;
    bid = (bid & 7) * (nwg >> 3) + (bid >> 3);
    const int gx = N >> 7;
    const int row0 = (bid / gx) * 128, col0 = (bid % gx) * 128;

    f32x4 acc[4][4] = {};
    const int nk = K >> 5;

    for (int kt = 0; kt < nk; ++kt) {
        const int k0 = kt << 5;
        // ---- stage A
        if constexpr (!AF32) {
            const bf16_t* Ab = (const bf16_t*)Aptr;
#pragma unroll
            for (int t = 0; t < 2; ++t) {
                const int c = wid * 2 + t;
                const int r = c * 16 + (lane >> 2);
                const int slot = (lane & 3) ^ ((r >> 1) & 3);       // inverse-swizzled source
                glds16(Ab + (size_t)(row0 + r) * lda + k0 + slot * 8,
                       (bf16_t*)smem + c * 512);
            }
        } else {
            const float* Af = (const float*)Aptr;
#pragma unroll
            for (int t = 0; t < 4; ++t) {
                const int c = wid * 4 + t;
                const int r = c * 8 + (lane >> 3);
                const int slot = (lane & 7) ^ (r & 7);
                glds16(Af + (size_t)(row0 + r) * lda + k0 + slot * 4,
                       (float*)smem + c * 256);
            }
        }
        // ---- stage B (always bf16 K-major)
#pragma unroll
        for (int t = 0; t < 2; ++t) {
            const int c = wid * 2 + t;
            const int r = c * 16 + (lane >> 2);
            const int slot = (lane & 3) ^ ((r >> 1) & 3);
            glds16(Bt + (size_t)(col0 + r) * ldb + k0 + slot * 8, sB + c * 512);
        }
        __syncthreads();

        // ---- fragments (swizzled ds_read) + MFMA
        bf16x8 af[4], bfr[4];
        const int l15 = lane & 15, kq = lane >> 4;
#pragma unroll
        for (int i = 0; i < 4; ++i) {
            const int br = wc * 64 + i * 16 + l15;
            bfr[i] = *(const bf16x8*)&sB[br * 32 + ((kq ^ ((br >> 1) & 3)) * 8)];
            const int ar = wr * 64 + i * 16 + l15;
            if constexpr (!AF32) {
                af[i] = *(const bf16x8*)((bf16_t*)smem + ar * 32 + ((kq ^ ((ar >> 1) & 3)) * 8));
            } else {
                const float* As = (const float*)smem + ar * 32;
                const int s0 = (kq * 2) ^ (ar & 7);
                const int s1 = (kq * 2 + 1) ^ (ar & 7);
                float4 u = *(const float4*)(As + s0 * 4);
                float4 v = *(const float4*)(As + s1 * 4);
                af[i][0] = (bf16_t)u.x; af[i][1] = (bf16_t)u.y;
                af[i][2] = (bf16_t)u.z; af[i][3] = (bf16_t)u.w;
                af[i][4] = (bf16_t)v.x; af[i][5] = (bf16_t)v.y;
                af[i][6] = (bf16_t)v.z; af[i][7] = (bf16_t)v.w;
            }
        }
#pragma unroll
        for (int i = 0; i < 4; ++i)
#pragma unroll
            for (int j = 0; j < 4; ++j)
                acc[i][j] = __builtin_amdgcn_mfma_f32_16x16x32_bf16(af[i], bfr[j], acc[i][j], 0, 0, 0);
        __syncthreads();
    }

    // ---- epilogue: C/D layout col = lane&15, row = 4*(lane>>4)+reg
    const int lr = (lane >> 4) * 4, lc = lane & 15;
#pragma unroll
    for (int i = 0; i < 4; ++i) {
#pragma unroll
        for (int j = 0; j < 4; ++j) {
#pragma unroll
            for (int r = 0; r < 4; ++r) {
                const int grow = row0 + wr * 64 + i * 16 + lr + r;
                const int gcol = col0 + wc * 64 + j * 16 + lc;
                float v = acc[i][j][r];
                if constexpr (EPI == 0) {
                    v += bias[gcol];
                    const float a = ((gcol >> 9) == 2) ? tanhf(v) : sigm(v);
                    bout[(size_t)grow * 2048 + gcol] = (bf16_t)a;
                } else if constexpr (EPI == 1) {
                    // bf16 logits packed into first half of each fp32 attn row slot
                    bout[(size_t)grow * 8192 + gcol] = (bf16_t)(v + bias[gcol]);
                } else {
                    const float ig = (float)gates[(size_t)grow * 2048 + gcol];
                    const float fg = (float)gates[(size_t)grow * 2048 + 512 + gcol];
                    const float cg = (float)gates[(size_t)grow * 2048 + 1024 + gcol];
                    const float og = (float)gates[(size_t)grow * 2048 + 1536 + gcol];
                    const float cv = cell[(size_t)grow * 512 + gcol];
                    const float ncv = fg * cv + ig * cg + 0.1f * v;
                    fout[(size_t)grow * 512 + gcol] = og * tanhf(ncv);
                    fout[(size_t)Bn * Hn + (size_t)grow * 512 + gcol] = ncv;
                }
            }
        }
    }
}

// Row softmax: reads bf16 logits packed in the row's first half, writes fp32 attn in place.
// Row-local, so bf16->fp32 in-place expansion is race-free.
__global__ void softmax_mid(float* __restrict__ attn)
{
    const int row = blockIdx.x;
    float* rp = attn + (size_t)row * 4096;
    const bf16_t* lp = (const bf16_t*)rp;
    const int tid = threadIdx.x;

    float v[16];
    {
        bf16x8 h0 = ((const bf16x8*)lp)[tid];
        bf16x8 h1 = ((const bf16x8*)lp)[tid + 256];
#pragma unroll
        for (int k = 0; k < 8; ++k) { v[k] = (float)h0[k]; v[8 + k] = (float)h1[k]; }
    }
    float mx = v[0];
#pragma unroll
    for (int k = 1; k < 16; ++k) mx = fmaxf(mx, v[k]);
#pragma unroll
    for (int off = 32; off > 0; off >>= 1) mx = fmaxf(mx, __shfl_xor(mx, off));
    __shared__ float smx[4], ssm[4];
    if ((tid & 63) == 0) smx[tid >> 6] = mx;
    __syncthreads();
    mx = fmaxf(fmaxf(smx[0], smx[1]), fmaxf(smx[2], smx[3]));

    float sum = 0.0f;
#pragma unroll
    for (int k = 0; k < 16; ++k) { v[k] = __expf(v[k] - mx); sum += v[k]; }
#pragma unroll
    for (int off = 32; off > 0; off >>= 1) sum += __shfl_xor(sum, off);
    if ((tid & 63) == 0) ssm[tid >> 6] = sum;
    __syncthreads();
    sum = ssm[0] + ssm[1] + ssm[2] + ssm[3];

    const float inv = 1.0f / sum;
    float4 o0 = { v[0] * inv,  v[1] * inv,  v[2] * inv,  v[3] * inv };
    float4 o1 = { v[4] * inv,  v[5] * inv,  v[6] * inv,  v[7] * inv };
    float4 o2 = { v[8] * inv,  v[9] * inv,  v[10] * inv, v[11] * inv };
    float4 o3 = { v[12] * inv, v[13] * inv, v[14] * inv, v[15] * inv };
    ((float4*)rp)[tid * 2]             = o0;
    ((float4*)rp)[tid * 2 + 1]         = o1;
    ((float4*)rp)[(tid + 256) * 2]     = o2;
    ((float4*)rp)[(tid + 256) * 2 + 1] = o3;
}

extern "C" void kernel_launch(void* const* d_in, const int* in_sizes, int n_in,
                              void* d_out, int out_size, void* d_ws, size_t ws_size,
                              hipStream_t stream)
{
    const float* input  = (const float*)d_in[0];   // (B, 512)
    const float* hidden = (const float*)d_in[1];   // (B, 512)
    const float* cell   = (const float*)d_in[2];   // (B, 512)
    const float* Wg     = (const float*)d_in[3];   // (1024, 2048)
    const float* bg     = (const float*)d_in[4];   // (2048,)
    const float* Wa     = (const float*)d_in[5];   // (512, 4096)
    const float* ba     = (const float*)d_in[6];   // (4096,)
    const float* Mem    = (const float*)d_in[7];   // (4096, 512)

    float* out  = (float*)d_out;
    float* attn = out + 2ull * Bn * Hn;            // (B, 4096) fp32 output region

    // ws layout (bf16): comb 33.6MB | WgT 4.2 | WaT 4.2 | MemT 4.2 | gates 67.1  = ~113.6 MB
    bf16_t* comb  = (bf16_t*)d_ws;                 // [B][1024]
    bf16_t* WgT   = comb + (size_t)Bn * 1024;      // [2048][1024]
    bf16_t* WaT   = WgT + (size_t)2048 * 1024;     // [4096][512]
    bf16_t* MemT  = WaT + (size_t)4096 * 512;      // [512][4096]
    bf16_t* gates = MemT + (size_t)512 * 4096;     // [B][2048]

    convert_comb<<<8192, 256, 0, stream>>>(input, hidden, comb);
    transpose_bf16<<<dim3(64, 32), 256, 0, stream>>>(Wg, WgT, 1024, 2048);
    transpose_bf16<<<dim3(128, 16), 256, 0, stream>>>(Wa, WaT, 512, 4096);
    transpose_bf16<<<dim3(16, 128), 256, 0, stream>>>(Mem, MemT, 4096, 512);

    // gates = act([x|h] @ Wg + bg)
    gemm_glds<0, false><<<2048, 256, 0, stream>>>(comb, 1024, WgT, 1024, bg, 1024, 2048,
                                                  gates, nullptr, nullptr, nullptr);
    // bf16 logits -> d_out attn slots (packed)
    gemm_glds<1, false><<<4096, 256, 0, stream>>>(comb + 512, 1024, WaT, 512, ba, 512, 4096,
                                                  (bf16_t*)attn, nullptr, nullptr, nullptr);
    // softmax in place (bf16 -> fp32)
    softmax_mid<<<Bn, 256, 0, stream>>>(attn);
    // mr = attn @ Mem fused with LSTM update
    gemm_glds<2, true><<<512, 256, 0, stream>>>(attn, 4096, MemT, 4096, nullptr, 4096, 512,
                                                nullptr, out, gates, cell);
}